// Round 5
// baseline (198.533 us; speedup 1.0000x reference)
//
#include <hip/hip_runtime.h>

// Volume rendering: 2 rays per wave-half-pair (32 lanes/ray, 4 samples/lane),
// DPP cross-lane ops, NONTEMPORAL loads+stores (round-3 win: single-use
// streams must bypass temporal cache allocation; volrend dropped 73 -> <59us).
// Round 4/5: 2 ray-pairs per wave, ALL 10 NT float4 loads issued up front,
// then both pairs computed back-to-back. Pair B's loads stay in flight under
// pair A's compute tail -> 2x per-wave MLP. (Round-4 submission failed on
// container acquisition — this is an unchanged resubmit.)

#define N_SAMPLES 128

typedef float f32x4 __attribute__((ext_vector_type(4)));

template <int CTRL, int ROWMASK = 0xf>
__device__ __forceinline__ float dpp_mov(float x, float oldv) {
    int r = __builtin_amdgcn_update_dpp(__float_as_int(oldv), __float_as_int(x),
                                        CTRL, ROWMASK, 0xf, false);
    return __int_as_float(r);
}

#define ROW_SHR1 0x111
#define ROW_SHR2 0x112
#define ROW_SHR4 0x114
#define ROW_SHR8 0x118
#define ROW_BCAST15 0x142
#define WAVE_SHL1 0x130
#define WAVE_SHR1 0x138

struct Frag {
    f32x4 z, dn, r0, r1, r2;
    float nx, ny, nz;
};

__device__ __forceinline__ void load_frag(Frag& f,
    const float* __restrict__ rgb, const float* __restrict__ density,
    const float* __restrict__ z_vals, const float* __restrict__ rays_d,
    int ray, int lr)
{
    const f32x4* z4 = (const f32x4*)(z_vals  + (size_t)ray * N_SAMPLES);
    const f32x4* d4 = (const f32x4*)(density + (size_t)ray * N_SAMPLES);
    const f32x4* r4 = (const f32x4*)(rgb     + (size_t)ray * N_SAMPLES * 3);
    f.z  = __builtin_nontemporal_load(z4 + lr);
    f.dn = __builtin_nontemporal_load(d4 + lr);
    // interleaved mapping: r0=[s0.r s0.g s0.b s1.r] r1=[s1.g s1.b s2.r s2.g]
    //                      r2=[s2.b s3.r s3.g s3.b]
    f.r0 = __builtin_nontemporal_load(r4 + 3 * lr + 0);
    f.r1 = __builtin_nontemporal_load(r4 + 3 * lr + 1);
    f.r2 = __builtin_nontemporal_load(r4 + 3 * lr + 2);
    // rays_d: broadcast within each 32-lane half, L1-served; keep temporal
    f.nx = rays_d[ray * 3 + 0];
    f.ny = rays_d[ray * 3 + 1];
    f.nz = rays_d[ray * 3 + 2];
}

__device__ __forceinline__ void compute_frag(const Frag& f, int ray, int lr,
    float* __restrict__ out_rgb, float* __restrict__ out_depth,
    float* __restrict__ out_w)
{
    float nrm = sqrtf(f.nx * f.nx + f.ny * f.ny + f.nz * f.nz);

    // dists: z.x of next lane (lane i <- lane i+1)
    float znext = dpp_mov<WAVE_SHL1>(f.z.x, 0.0f);
    bool last = (lr == 31);
    float dist0 = (f.z.y - f.z.x) * nrm;
    float dist1 = (f.z.z - f.z.y) * nrm;
    float dist2 = (f.z.w - f.z.z) * nrm;
    float dist3 = last ? (1e10f * nrm) : ((znext - f.z.w) * nrm);

    float e0 = __expf(-fmaxf(f.dn.x, 0.0f) * dist0);
    float e1 = __expf(-fmaxf(f.dn.y, 0.0f) * dist1);
    float e2 = __expf(-fmaxf(f.dn.z, 0.0f) * dist2);
    float e3 = __expf(-fmaxf(f.dn.w, 0.0f) * dist3);
    float a0 = 1.0f - e0, a1 = 1.0f - e1, a2 = 1.0f - e2, a3 = 1.0f - e3;
    float p0 = e0 + 1e-10f, p1 = e1 + 1e-10f, p2 = e2 + 1e-10f, p3 = e3 + 1e-10f;

    // exclusive prefix product across the 32 lanes of this ray.
    // ROW_BCAST15 with row_mask=0xA stays within each ray.
    float x = p0 * p1 * p2 * p3;
    x *= dpp_mov<ROW_SHR1>(x, 1.0f);
    x *= dpp_mov<ROW_SHR2>(x, 1.0f);
    x *= dpp_mov<ROW_SHR4>(x, 1.0f);
    x *= dpp_mov<ROW_SHR8>(x, 1.0f);
    x *= dpp_mov<ROW_BCAST15, 0xA>(x, 1.0f);
    float ex = dpp_mov<WAVE_SHR1>(x, 1.0f);
    if (lr == 0) ex = 1.0f;

    float T0 = ex;
    float T1 = T0 * p0;
    float T2 = T1 * p1;
    float T3 = T2 * p2;
    float w0 = a0 * T0, w1 = a1 * T1, w2 = a2 * T2, w3 = a3 * T3;

    f32x4 wv = { w0, w1, w2, w3 };
    __builtin_nontemporal_store(wv, (f32x4*)(out_w + (size_t)ray * N_SAMPLES) + lr);

    float cr = w0 * f.r0.x + w1 * f.r0.w + w2 * f.r1.z + w3 * f.r2.y;
    float cg = w0 * f.r0.y + w1 * f.r1.x + w2 * f.r1.w + w3 * f.r2.z;
    float cb = w0 * f.r0.z + w1 * f.r1.y + w2 * f.r2.x + w3 * f.r2.w;
    float cd = w0 * f.z.x  + w1 * f.z.y  + w2 * f.z.z  + w3 * f.z.w;

    cr += dpp_mov<ROW_SHR1>(cr, 0.0f);
    cg += dpp_mov<ROW_SHR1>(cg, 0.0f);
    cb += dpp_mov<ROW_SHR1>(cb, 0.0f);
    cd += dpp_mov<ROW_SHR1>(cd, 0.0f);
    cr += dpp_mov<ROW_SHR2>(cr, 0.0f);
    cg += dpp_mov<ROW_SHR2>(cg, 0.0f);
    cb += dpp_mov<ROW_SHR2>(cb, 0.0f);
    cd += dpp_mov<ROW_SHR2>(cd, 0.0f);
    cr += dpp_mov<ROW_SHR4>(cr, 0.0f);
    cg += dpp_mov<ROW_SHR4>(cg, 0.0f);
    cb += dpp_mov<ROW_SHR4>(cb, 0.0f);
    cd += dpp_mov<ROW_SHR4>(cd, 0.0f);
    cr += dpp_mov<ROW_SHR8>(cr, 0.0f);
    cg += dpp_mov<ROW_SHR8>(cg, 0.0f);
    cb += dpp_mov<ROW_SHR8>(cb, 0.0f);
    cd += dpp_mov<ROW_SHR8>(cd, 0.0f);
    cr += dpp_mov<ROW_BCAST15, 0xA>(cr, 0.0f);
    cg += dpp_mov<ROW_BCAST15, 0xA>(cg, 0.0f);
    cb += dpp_mov<ROW_BCAST15, 0xA>(cb, 0.0f);
    cd += dpp_mov<ROW_BCAST15, 0xA>(cd, 0.0f);

    if (lr == 31) {
        __builtin_nontemporal_store(cr, out_rgb + ray * 3 + 0);
        __builtin_nontemporal_store(cg, out_rgb + ray * 3 + 1);
        __builtin_nontemporal_store(cb, out_rgb + ray * 3 + 2);
        __builtin_nontemporal_store(cd, out_depth + ray);
    }
}

__global__ __launch_bounds__(256) void volrend_kernel(
    const float* __restrict__ rgb,      // (n_rays, 128, 3)
    const float* __restrict__ density,  // (n_rays, 128, 1)
    const float* __restrict__ z_vals,   // (n_rays, 128)
    const float* __restrict__ rays_d,   // (n_rays, 3)
    float* __restrict__ out_rgb,        // (n_rays, 3)
    float* __restrict__ out_depth,      // (n_rays,)
    float* __restrict__ out_w,          // (n_rays, 128)
    int n_rays)
{
    int tid  = blockIdx.x * blockDim.x + threadIdx.x;
    int wid  = tid >> 6;          // global wave id
    int lane = threadIdx.x & 63;
    int lr   = lane & 31;
    int half = lane >> 5;

    int n_pairs = (n_rays + 1) >> 1;
    int pairA = wid * 2;
    int pairB = wid * 2 + 1;
    if (pairA >= n_pairs) return;   // wave-uniform

    int rayA = pairA * 2 + half;
    int rayB = pairB * 2 + half;
    bool doA = rayA < n_rays;
    bool doB = (pairB < n_pairs) && (rayB < n_rays);

    Frag fA, fB;
    // issue ALL loads before any compute: 10 NT float4 loads in flight
    if (doA) load_frag(fA, rgb, density, z_vals, rays_d, rayA, lr);
    if (doB) load_frag(fB, rgb, density, z_vals, rays_d, rayB, lr);

    if (doA) compute_frag(fA, rayA, lr, out_rgb, out_depth, out_w);
    if (doB) compute_frag(fB, rayB, lr, out_rgb, out_depth, out_w);
}

extern "C" void kernel_launch(void* const* d_in, const int* in_sizes, int n_in,
                              void* d_out, int out_size, void* d_ws, size_t ws_size,
                              hipStream_t stream) {
    const float* rgb     = (const float*)d_in[0];
    const float* density = (const float*)d_in[1];
    const float* z_vals  = (const float*)d_in[2];
    const float* rays_d  = (const float*)d_in[3];

    int n_rays = in_sizes[3] / 3;   // rays_d is (n_rays, 3)

    float* out       = (float*)d_out;
    float* out_rgb   = out;                          // n_rays*3
    float* out_depth = out + (size_t)n_rays * 3;     // n_rays
    float* out_w     = out_depth + n_rays;           // n_rays*128

    int block = 256;                       // 4 waves/block, 2 pairs/wave
    int waves_per_block = block / 64;
    int n_pairs = (n_rays + 1) / 2;
    int n_waves = (n_pairs + 1) / 2;
    int grid = (n_waves + waves_per_block - 1) / waves_per_block;

    volrend_kernel<<<grid, block, 0, stream>>>(rgb, density, z_vals, rays_d,
                                               out_rgb, out_depth, out_w,
                                               n_rays);
}

// Round 6
// 192.010 us; speedup vs baseline: 1.0340x; 1.0340x over previous
//
#include <hip/hip_runtime.h>

// Volume rendering: 2 rays per wave (32 lanes/ray, 4 samples/lane), DPP
// cross-lane ops, NONTEMPORAL loads+stores (round-3 win), 1 ray-pair per wave
// (round-3 shape; round-5 showed 2-pair batching is neutral/negative).
// Round 6 change: dense rgb loads + LDS transpose (round-1 structure) brought
// back, now combined with NT. Rationale: round-1's null was measured under
// the temporal-cache wall that round 3 removed. With NT (no L1 allocation),
// strided rgb loads issue 36 line-requests per half-wave to 12 distinct
// lines (3 instructions x all 12 lines each); dense loads + LDS transpose
// cut that to 12. rgb is 60% of read bytes — this is the last untested
// pattern x policy combination.

#define N_SAMPLES 128

typedef float f32x4 __attribute__((ext_vector_type(4)));

template <int CTRL, int ROWMASK = 0xf>
__device__ __forceinline__ float dpp_mov(float x, float oldv) {
    int r = __builtin_amdgcn_update_dpp(__float_as_int(oldv), __float_as_int(x),
                                        CTRL, ROWMASK, 0xf, false);
    return __int_as_float(r);
}

#define ROW_SHR1 0x111
#define ROW_SHR2 0x112
#define ROW_SHR4 0x114
#define ROW_SHR8 0x118
#define ROW_BCAST15 0x142
#define WAVE_SHL1 0x130
#define WAVE_SHR1 0x138

__global__ __launch_bounds__(256) void volrend_kernel(
    const float* __restrict__ rgb,      // (n_rays, 128, 3)
    const float* __restrict__ density,  // (n_rays, 128, 1)
    const float* __restrict__ z_vals,   // (n_rays, 128)
    const float* __restrict__ rays_d,   // (n_rays, 3)
    float* __restrict__ out_rgb,        // (n_rays, 3)
    float* __restrict__ out_depth,      // (n_rays,)
    float* __restrict__ out_w,          // (n_rays, 128)
    int n_rays)
{
    // 3KB rgb transpose buffer per wave; 12KB/block (8 blocks/CU by threads).
    __shared__ f32x4 lds_rgb[4][192];

    int tid  = blockIdx.x * blockDim.x + threadIdx.x;
    int wid  = tid >> 6;          // global wave id == pair id
    int lane = threadIdx.x & 63;
    int lr   = lane & 31;
    int half = lane >> 5;
    f32x4* buf = lds_rgb[threadIdx.x >> 6];

    int n_pairs = (n_rays + 1) >> 1;
    if (wid >= n_pairs) return;   // wave-uniform

    int ray = wid * 2 + half;
    if (ray >= n_rays) return;    // tail half-wave (DPP edges masked by exec)

    // ---- loads: nontemporal, all lane-DENSE (each instr = contiguous 512B/half) ----
    const f32x4* z4 = (const f32x4*)(z_vals  + (size_t)ray * N_SAMPLES);
    const f32x4* d4 = (const f32x4*)(density + (size_t)ray * N_SAMPLES);
    const f32x4* r4 = (const f32x4*)(rgb     + (size_t)ray * N_SAMPLES * 3);
    f32x4 z  = __builtin_nontemporal_load(z4 + lr);
    f32x4 dn = __builtin_nontemporal_load(d4 + lr);
    f32x4 r0 = __builtin_nontemporal_load(r4 + lr);        // dense chunk 0
    f32x4 r1 = __builtin_nontemporal_load(r4 + lr + 32);   // dense chunk 1
    f32x4 r2 = __builtin_nontemporal_load(r4 + lr + 64);   // dense chunk 2
    float nx = rays_d[ray * 3 + 0];
    float ny = rays_d[ray * 3 + 1];
    float nz = rays_d[ray * 3 + 2];

    // ---- LDS transpose: chunk k, half h, lane l -> slot k*64 + h*32 + l ----
    buf[      half * 32 + lr] = r0;
    buf[ 64 + half * 32 + lr] = r1;
    buf[128 + half * 32 + lr] = r2;
    // same-wave DS ops are in-order; no barrier needed (round-1 verified,
    // SQ_LDS_BANK_CONFLICT measured 0 for this layout).

    float nrm = sqrtf(nx * nx + ny * ny + nz * nz);

    // dists: z.x of next lane (lane i <- lane i+1)
    float znext = dpp_mov<WAVE_SHL1>(z.x, 0.0f);
    bool last = (lr == 31);
    float dist0 = (z.y - z.x) * nrm;
    float dist1 = (z.z - z.y) * nrm;
    float dist2 = (z.w - z.z) * nrm;
    float dist3 = last ? (1e10f * nrm) : ((znext - z.w) * nrm);

    float e0 = __expf(-fmaxf(dn.x, 0.0f) * dist0);
    float e1 = __expf(-fmaxf(dn.y, 0.0f) * dist1);
    float e2 = __expf(-fmaxf(dn.z, 0.0f) * dist2);
    float e3 = __expf(-fmaxf(dn.w, 0.0f) * dist3);
    float a0 = 1.0f - e0, a1 = 1.0f - e1, a2 = 1.0f - e2, a3 = 1.0f - e3;
    float p0 = e0 + 1e-10f, p1 = e1 + 1e-10f, p2 = e2 + 1e-10f, p3 = e3 + 1e-10f;

    // transposed rgb read-back: q_j == r4[3*lr + j] of this ray
    // interleaved mapping: q0=[s0.r s0.g s0.b s1.r] q1=[s1.g s1.b s2.r s2.g]
    //                      q2=[s2.b s3.r s3.g s3.b]
    int m = 3 * lr;
    f32x4 q0 = buf[((m    ) >> 5) * 64 + half * 32 + ((m    ) & 31)];
    f32x4 q1 = buf[((m + 1) >> 5) * 64 + half * 32 + ((m + 1) & 31)];
    f32x4 q2 = buf[((m + 2) >> 5) * 64 + half * 32 + ((m + 2) & 31)];

    // exclusive prefix product across the 32 lanes of this ray.
    // ROW_BCAST15 with row_mask=0xA stays within each ray.
    float x = p0 * p1 * p2 * p3;
    x *= dpp_mov<ROW_SHR1>(x, 1.0f);
    x *= dpp_mov<ROW_SHR2>(x, 1.0f);
    x *= dpp_mov<ROW_SHR4>(x, 1.0f);
    x *= dpp_mov<ROW_SHR8>(x, 1.0f);
    x *= dpp_mov<ROW_BCAST15, 0xA>(x, 1.0f);
    float ex = dpp_mov<WAVE_SHR1>(x, 1.0f);
    if (lr == 0) ex = 1.0f;

    float T0 = ex;
    float T1 = T0 * p0;
    float T2 = T1 * p1;
    float T3 = T2 * p2;
    float w0 = a0 * T0, w1 = a1 * T1, w2 = a2 * T2, w3 = a3 * T3;

    f32x4 wv = { w0, w1, w2, w3 };
    __builtin_nontemporal_store(wv, (f32x4*)(out_w + (size_t)ray * N_SAMPLES) + lr);

    float cr = w0 * q0.x + w1 * q0.w + w2 * q1.z + w3 * q2.y;
    float cg = w0 * q0.y + w1 * q1.x + w2 * q1.w + w3 * q2.z;
    float cb = w0 * q0.z + w1 * q1.y + w2 * q2.x + w3 * q2.w;
    float cd = w0 * z.x  + w1 * z.y  + w2 * z.z  + w3 * z.w;

    cr += dpp_mov<ROW_SHR1>(cr, 0.0f);
    cg += dpp_mov<ROW_SHR1>(cg, 0.0f);
    cb += dpp_mov<ROW_SHR1>(cb, 0.0f);
    cd += dpp_mov<ROW_SHR1>(cd, 0.0f);
    cr += dpp_mov<ROW_SHR2>(cr, 0.0f);
    cg += dpp_mov<ROW_SHR2>(cg, 0.0f);
    cb += dpp_mov<ROW_SHR2>(cb, 0.0f);
    cd += dpp_mov<ROW_SHR2>(cd, 0.0f);
    cr += dpp_mov<ROW_SHR4>(cr, 0.0f);
    cg += dpp_mov<ROW_SHR4>(cg, 0.0f);
    cb += dpp_mov<ROW_SHR4>(cb, 0.0f);
    cd += dpp_mov<ROW_SHR4>(cd, 0.0f);
    cr += dpp_mov<ROW_SHR8>(cr, 0.0f);
    cg += dpp_mov<ROW_SHR8>(cg, 0.0f);
    cb += dpp_mov<ROW_SHR8>(cb, 0.0f);
    cd += dpp_mov<ROW_SHR8>(cd, 0.0f);
    cr += dpp_mov<ROW_BCAST15, 0xA>(cr, 0.0f);
    cg += dpp_mov<ROW_BCAST15, 0xA>(cg, 0.0f);
    cb += dpp_mov<ROW_BCAST15, 0xA>(cb, 0.0f);
    cd += dpp_mov<ROW_BCAST15, 0xA>(cd, 0.0f);

    if (lr == 31) {
        __builtin_nontemporal_store(cr, out_rgb + ray * 3 + 0);
        __builtin_nontemporal_store(cg, out_rgb + ray * 3 + 1);
        __builtin_nontemporal_store(cb, out_rgb + ray * 3 + 2);
        __builtin_nontemporal_store(cd, out_depth + ray);
    }
}

extern "C" void kernel_launch(void* const* d_in, const int* in_sizes, int n_in,
                              void* d_out, int out_size, void* d_ws, size_t ws_size,
                              hipStream_t stream) {
    const float* rgb     = (const float*)d_in[0];
    const float* density = (const float*)d_in[1];
    const float* z_vals  = (const float*)d_in[2];
    const float* rays_d  = (const float*)d_in[3];

    int n_rays = in_sizes[3] / 3;   // rays_d is (n_rays, 3)

    float* out       = (float*)d_out;
    float* out_rgb   = out;                          // n_rays*3
    float* out_depth = out + (size_t)n_rays * 3;     // n_rays
    float* out_w     = out_depth + n_rays;           // n_rays*128

    int block = 256;                       // 4 waves/block, 1 pair/wave
    int waves_per_block = block / 64;
    int n_pairs = (n_rays + 1) / 2;
    int grid = (n_pairs + waves_per_block - 1) / waves_per_block;

    volrend_kernel<<<grid, block, 0, stream>>>(rgb, density, z_vals, rays_d,
                                               out_rgb, out_depth, out_w,
                                               n_rays);
}